// Round 1
// baseline (459.852 us; speedup 1.0000x reference)
//
#include <hip/hip_runtime.h>

#define SS 1024
#define BB 4096
#define HH 8

// fast sigmoid/tanh: v_exp_f32 + v_rcp_f32 based, ~1e-7 rel error,
// far below the 1.95e-2 absmax threshold even accumulated over 1024 steps.
__device__ __forceinline__ float fast_sigmoid(float x) {
    return __fdividef(1.0f, 1.0f + __expf(-x));
}
__device__ __forceinline__ float fast_tanh(float x) {
    // tanh(x) = 1 - 2/(exp(2x)+1); saturates correctly at +-1 for |x| large.
    return 1.0f - __fdividef(2.0f, __expf(2.0f * x) + 1.0f);
}

// 8 lanes per batch element (lane j = hidden index), 8 batches per wave.
// Weights for this lane's 3 gate rows live in registers; h-vector gathered
// across the 8-lane group via static ds_swizzle broadcasts.
__global__ __launch_bounds__(64, 1) void gru_kernel(
    const float* __restrict__ x,
    const float* __restrict__ w_ih,
    const float* __restrict__ w_hh,
    const float* __restrict__ b_ih,
    const float* __restrict__ b_hh,
    float* __restrict__ out)
{
    const int lane = threadIdx.x;          // 0..63
    const int j = lane & 7;                // hidden index within batch element
    const int bg = (blockIdx.x << 3) + (lane >> 3);  // batch element

    // Per-lane gate rows: r = rows [0,8), z = rows [8,16), n = rows [16,24).
    float wri[8], wzi[8], wni[8], wrh[8], wzh[8], wnh[8];
    #pragma unroll
    for (int i = 0; i < 8; ++i) {
        wri[i] = w_ih[j * 8 + i];
        wzi[i] = w_ih[(8 + j) * 8 + i];
        wni[i] = w_ih[(16 + j) * 8 + i];
        wrh[i] = w_hh[j * 8 + i];
        wzh[i] = w_hh[(8 + j) * 8 + i];
        wnh[i] = w_hh[(16 + j) * 8 + i];
    }
    const float bri = b_ih[j], bzi = b_ih[8 + j], bni = b_ih[16 + j];
    const float brh = b_hh[j], bzh = b_hh[8 + j], bnh = b_hh[16 + j];

    const float* xp = x + (size_t)bg * HH;                       // &x[0][bg][0]
    float* op = out + (size_t)bg * HH + j;                       // outputs[s][bg][j]
    float* hlast = out + (size_t)SS * BB * HH + (size_t)bg * HH + j;

    float h = 0.0f;

    // prefetch x for s=0 (all 8 lanes of a group read the same 32B; coalesced
    // across the wave: 256B contiguous)
    float4 xa = *(const float4*)xp;
    float4 xb = *(const float4*)(xp + 4);

    for (int s = 0; s < SS; ++s) {
        float xv[8] = {xa.x, xa.y, xa.z, xa.w, xb.x, xb.y, xb.z, xb.w};

        // prefetch x for s+1 early — independent of h, hides HBM latency
        {
            const int sn = (s + 1 < SS) ? (s + 1) : (SS - 1);
            const float* xnp = xp + (size_t)sn * (BB * HH);
            xa = *(const float4*)xnp;
            xb = *(const float4*)(xnp + 4);
        }

        // input-side gate pre-activations (24 FMA)
        float accr = bri, accz = bzi, accn = bni;
        #pragma unroll
        for (int i = 0; i < 8; ++i) {
            accr = fmaf(xv[i], wri[i], accr);
            accz = fmaf(xv[i], wzi[i], accz);
            accn = fmaf(xv[i], wni[i], accn);
        }

        // gather group's h vector: src_lane = (lane & 0x18) | i  (BitMode:
        // and=0x18, or=i, xor=0 -> imm = (i<<5)|0x18)
        const int hbits = __float_as_int(h);
        float hv[8];
        hv[0] = __int_as_float(__builtin_amdgcn_ds_swizzle(hbits, 0x0018));
        hv[1] = __int_as_float(__builtin_amdgcn_ds_swizzle(hbits, 0x0038));
        hv[2] = __int_as_float(__builtin_amdgcn_ds_swizzle(hbits, 0x0058));
        hv[3] = __int_as_float(__builtin_amdgcn_ds_swizzle(hbits, 0x0078));
        hv[4] = __int_as_float(__builtin_amdgcn_ds_swizzle(hbits, 0x0098));
        hv[5] = __int_as_float(__builtin_amdgcn_ds_swizzle(hbits, 0x00B8));
        hv[6] = __int_as_float(__builtin_amdgcn_ds_swizzle(hbits, 0x00D8));
        hv[7] = __int_as_float(__builtin_amdgcn_ds_swizzle(hbits, 0x00F8));

        // hidden-side gate pre-activations (24 FMA)
        float hr = brh, hz = bzh, hn = bnh;
        #pragma unroll
        for (int i = 0; i < 8; ++i) {
            hr = fmaf(hv[i], wrh[i], hr);
            hz = fmaf(hv[i], wzh[i], hz);
            hn = fmaf(hv[i], wnh[i], hn);
        }

        const float r = fast_sigmoid(accr + hr);
        const float z = fast_sigmoid(accz + hz);
        const float n = fast_tanh(accn + r * hn);
        h = (1.0f - z) * n + z * h;

        // coalesced: wave's 64 lanes write 256B contiguous
        op[(size_t)s * (BB * HH)] = h;
    }
    *hlast = h;
}

extern "C" void kernel_launch(void* const* d_in, const int* in_sizes, int n_in,
                              void* d_out, int out_size, void* d_ws, size_t ws_size,
                              hipStream_t stream) {
    const float* x    = (const float*)d_in[0];
    const float* w_ih = (const float*)d_in[1];
    const float* w_hh = (const float*)d_in[2];
    const float* b_ih = (const float*)d_in[3];
    const float* b_hh = (const float*)d_in[4];
    float* out = (float*)d_out;
    gru_kernel<<<BB / 8, 64, 0, stream>>>(x, w_ih, w_hh, b_ih, b_hh, out);
}

// Round 2
// 238.733 us; speedup vs baseline: 1.9262x; 1.9262x over previous
//
#include <hip/hip_runtime.h>

#define SS 1024
#define BB 4096
#define HH 8
#define XSTRIDE (BB * HH)   // floats per timestep slice

// Raw-HW transcendentals: v_exp_f32 (2^x) + v_rcp_f32. ~1e-6 rel error,
// accumulated absmax in round 1 was 3.9e-3 vs 1.95e-2 threshold.
__device__ __forceinline__ float fsig(float x) {
    return __builtin_amdgcn_rcpf(1.0f + __builtin_amdgcn_exp2f(-1.4426950408889634f * x));
}
__device__ __forceinline__ float ftanh(float x) {
    return 1.0f - 2.0f * __builtin_amdgcn_rcpf(1.0f + __builtin_amdgcn_exp2f(2.8853900817779268f * x));
}

// One GRU step. Consumes hv[] (previous h broadcast across the 8-lane group),
// produces h, refreshes hv via ds_swizzle immediately (so the ~120cyc DS
// latency overlaps the NEXT step's independent x-side dots + the store).
#define GSTEP(X0, X1, SIDX) do {                                                       \
    const float xv_[8] = {(X0).x,(X0).y,(X0).z,(X0).w,(X1).x,(X1).y,(X1).z,(X1).w};    \
    float ar_ = bri, az_ = bzi, an_ = bni;                                             \
    _Pragma("unroll")                                                                  \
    for (int i_ = 0; i_ < 8; ++i_) {                                                   \
        ar_ = fmaf(xv_[i_], wri[i_], ar_);                                             \
        az_ = fmaf(xv_[i_], wzi[i_], az_);                                             \
        an_ = fmaf(xv_[i_], wni[i_], an_);                                             \
    }                                                                                  \
    float hr_ = brh, hz_ = bzh, hn_ = bnh;                                             \
    _Pragma("unroll")                                                                  \
    for (int i_ = 0; i_ < 8; ++i_) {                                                   \
        hr_ = fmaf(hv[i_], wrh[i_], hr_);                                              \
        hz_ = fmaf(hv[i_], wzh[i_], hz_);                                              \
        hn_ = fmaf(hv[i_], wnh[i_], hn_);                                              \
    }                                                                                  \
    const float r_ = fsig(ar_ + hr_);                                                  \
    const float z_ = fsig(az_ + hz_);                                                  \
    const float n_ = ftanh(an_ + r_ * hn_);                                            \
    h = n_ + z_ * (h - n_);                                                            \
    const int hb_ = __float_as_int(h);                                                 \
    hv[0] = __int_as_float(__builtin_amdgcn_ds_swizzle(hb_, 0x0018));                  \
    hv[1] = __int_as_float(__builtin_amdgcn_ds_swizzle(hb_, 0x0038));                  \
    hv[2] = __int_as_float(__builtin_amdgcn_ds_swizzle(hb_, 0x0058));                  \
    hv[3] = __int_as_float(__builtin_amdgcn_ds_swizzle(hb_, 0x0078));                  \
    hv[4] = __int_as_float(__builtin_amdgcn_ds_swizzle(hb_, 0x0098));                  \
    hv[5] = __int_as_float(__builtin_amdgcn_ds_swizzle(hb_, 0x00B8));                  \
    hv[6] = __int_as_float(__builtin_amdgcn_ds_swizzle(hb_, 0x00D8));                  \
    hv[7] = __int_as_float(__builtin_amdgcn_ds_swizzle(hb_, 0x00F8));                  \
    op[(size_t)(SIDX) * XSTRIDE] = h;                                                  \
} while (0)

// 8 lanes per batch element (lane j = hidden index), 8 batches per wave.
// Weights in registers; x double-buffered 8 steps deep (prefetch distance
// 8-16 steps ~= 1600+ cycles, fully covering HBM latency).
__global__ __launch_bounds__(64, 1) void gru_kernel(
    const float* __restrict__ x,
    const float* __restrict__ w_ih,
    const float* __restrict__ w_hh,
    const float* __restrict__ b_ih,
    const float* __restrict__ b_hh,
    float* __restrict__ out)
{
    const int lane = threadIdx.x;
    const int j = lane & 7;
    const int bg = (blockIdx.x << 3) + (lane >> 3);

    float wri[8], wzi[8], wni[8], wrh[8], wzh[8], wnh[8];
    #pragma unroll
    for (int i = 0; i < 8; ++i) {
        wri[i] = w_ih[j * 8 + i];
        wzi[i] = w_ih[(8 + j) * 8 + i];
        wni[i] = w_ih[(16 + j) * 8 + i];
        wrh[i] = w_hh[j * 8 + i];
        wzh[i] = w_hh[(8 + j) * 8 + i];
        wnh[i] = w_hh[(16 + j) * 8 + i];
    }
    const float bri = b_ih[j], bzi = b_ih[8 + j], bni = b_ih[16 + j];
    const float brh = b_hh[j], bzh = b_hh[8 + j], bnh = b_hh[16 + j];

    const float* xp = x + (size_t)bg * HH;
    float* op = out + (size_t)bg * HH + j;
    float* hlast = out + (size_t)SS * BB * HH + (size_t)bg * HH + j;

    float4 xA[16], xB[16];

    // prologue: group 0 -> A (cold start: one exposed HBM latency, tolerable)
    #pragma unroll
    for (int u = 0; u < 8; ++u) {
        const float* p = xp + (size_t)u * XSTRIDE;
        xA[2 * u]     = *(const float4*)p;
        xA[2 * u + 1] = *(const float4*)(p + 4);
    }

    float h = 0.0f;
    float hv[8] = {0, 0, 0, 0, 0, 0, 0, 0};  // h==0 at step 0, no swizzle needed

    // 128 groups of 8 steps; ping-pong A/B so no register copies.
    for (int g = 0; g < 128; g += 2) {
        // issue loads for group g+1 -> B (used 8 steps from now)
        {
            const float* bp = xp + (size_t)(g + 1) * 8 * XSTRIDE;
            #pragma unroll
            for (int u = 0; u < 8; ++u) {
                const float* p = bp + (size_t)u * XSTRIDE;
                xB[2 * u]     = *(const float4*)p;
                xB[2 * u + 1] = *(const float4*)(p + 4);
            }
        }
        // process group g from A
        #pragma unroll
        for (int u = 0; u < 8; ++u) GSTEP(xA[2 * u], xA[2 * u + 1], g * 8 + u);
        // issue loads for group g+2 -> A (dummy reload of last group at the end)
        {
            const int ga = (g + 2 < 128) ? (g + 2) : 127;
            const float* ap = xp + (size_t)ga * 8 * XSTRIDE;
            #pragma unroll
            for (int u = 0; u < 8; ++u) {
                const float* p = ap + (size_t)u * XSTRIDE;
                xA[2 * u]     = *(const float4*)p;
                xA[2 * u + 1] = *(const float4*)(p + 4);
            }
        }
        // process group g+1 from B
        #pragma unroll
        for (int u = 0; u < 8; ++u) GSTEP(xB[2 * u], xB[2 * u + 1], (g + 1) * 8 + u);
    }
    *hlast = h;
}

extern "C" void kernel_launch(void* const* d_in, const int* in_sizes, int n_in,
                              void* d_out, int out_size, void* d_ws, size_t ws_size,
                              hipStream_t stream) {
    const float* x    = (const float*)d_in[0];
    const float* w_ih = (const float*)d_in[1];
    const float* w_hh = (const float*)d_in[2];
    const float* b_ih = (const float*)d_in[3];
    const float* b_hh = (const float*)d_in[4];
    float* out = (float*)d_out;
    gru_kernel<<<BB / 8, 64, 0, stream>>>(x, w_ih, w_hh, b_ih, b_hh, out);
}

// Round 3
// 154.512 us; speedup vs baseline: 2.9762x; 1.5451x over previous
//
#include <hip/hip_runtime.h>

#define SS 1024
#define BB 4096
#define HH 8
#define XSTRIDE (BB * HH)   // floats per timestep slice

typedef float f32x2 __attribute__((ext_vector_type(2)));

// Raw-HW transcendentals: v_exp_f32 (2^x) + v_rcp_f32. Round-2 accumulated
// absmax was 3.9e-3 vs 1.95e-2 threshold.
__device__ __forceinline__ float fsig(float x) {
    return __builtin_amdgcn_rcpf(1.0f + __builtin_amdgcn_exp2f(-1.4426950408889634f * x));
}
__device__ __forceinline__ float ftanh(float x) {
    return 1.0f - 2.0f * __builtin_amdgcn_rcpf(1.0f + __builtin_amdgcn_exp2f(2.8853900817779268f * x));
}

// DPP cross-lane (VALU pipe, no DS): xor1/xor2 via quad_perm, xor7 via
// row_half_mirror (i -> 7-i == i^7 within each aligned 8-lane half-row).
__device__ __forceinline__ int dpp_x1(int v) {
    return __builtin_amdgcn_mov_dpp(v, 0xB1, 0xF, 0xF, true);   // quad_perm [1,0,3,2]
}
__device__ __forceinline__ int dpp_x2(int v) {
    return __builtin_amdgcn_mov_dpp(v, 0x4E, 0xF, 0xF, true);   // quad_perm [2,3,0,1]
}
__device__ __forceinline__ int dpp_x7(int v) {
    return __builtin_amdgcn_mov_dpp(v, 0x141, 0xF, 0xF, true);  // row_half_mirror
}

// Butterfly register m holds h[j ^ MK[m]] — weights are loaded pre-permuted
// to match, so the dot products pair correctly.
__device__ __constant__ int MK_[8] = {0, 1, 2, 3, 7, 6, 5, 4};

// One GRU step: consumes hv2[4] (group's h values, butterfly order),
// produces h, refreshes hv2 via DPP butterfly (depth 3, ~15 cyc).
#define GSTEP(X0, X1, SIDX) do {                                                       \
    f32x2 xr2 = {bri, 0.0f}, xz2 = {bzi, 0.0f}, xn2 = {bni, 0.0f};                     \
    f32x2 xp0 = {(X0).x, (X0).y}, xp1 = {(X0).z, (X0).w};                              \
    f32x2 xp2 = {(X1).x, (X1).y}, xp3 = {(X1).z, (X1).w};                              \
    f32x2 xps[4] = {xp0, xp1, xp2, xp3};                                               \
    _Pragma("unroll")                                                                  \
    for (int p_ = 0; p_ < 4; ++p_) {                                                   \
        xr2 = __builtin_elementwise_fma(xps[p_], wri[p_], xr2);                        \
        xz2 = __builtin_elementwise_fma(xps[p_], wzi[p_], xz2);                        \
        xn2 = __builtin_elementwise_fma(xps[p_], wni[p_], xn2);                        \
    }                                                                                  \
    f32x2 hr2 = {brh, 0.0f}, hz2 = {bzh, 0.0f}, hn2 = {bnh, 0.0f};                     \
    _Pragma("unroll")                                                                  \
    for (int p_ = 0; p_ < 4; ++p_) {                                                   \
        hr2 = __builtin_elementwise_fma(hv2[p_], wrh[p_], hr2);                        \
        hz2 = __builtin_elementwise_fma(hv2[p_], wzh[p_], hz2);                        \
        hn2 = __builtin_elementwise_fma(hv2[p_], wnh[p_], hn2);                        \
    }                                                                                  \
    const float r_ = fsig(xr2.x + xr2.y + hr2.x + hr2.y);                              \
    const float z_ = fsig(xz2.x + xz2.y + hz2.x + hz2.y);                              \
    const float n_ = ftanh(xn2.x + xn2.y + r_ * (hn2.x + hn2.y));                      \
    h = n_ + z_ * (h - n_);                                                            \
    const int hb_ = __float_as_int(h);                                                 \
    const int t1_ = dpp_x1(hb_);   /* h[j^1] */                                        \
    const int t2_ = dpp_x2(hb_);   /* h[j^2] */                                        \
    const int t3_ = dpp_x2(t1_);   /* h[j^3] */                                        \
    const int t4_ = dpp_x7(hb_);   /* h[j^7] */                                        \
    const int t5_ = dpp_x7(t1_);   /* h[j^6] */                                        \
    const int t6_ = dpp_x7(t2_);   /* h[j^5] */                                        \
    const int t7_ = dpp_x7(t3_);   /* h[j^4] */                                        \
    hv2[0] = (f32x2){h, __int_as_float(t1_)};                                          \
    hv2[1] = (f32x2){__int_as_float(t2_), __int_as_float(t3_)};                        \
    hv2[2] = (f32x2){__int_as_float(t4_), __int_as_float(t5_)};                        \
    hv2[3] = (f32x2){__int_as_float(t6_), __int_as_float(t7_)};                        \
    op[(size_t)(SIDX) * XSTRIDE] = h;                                                  \
} while (0)

__global__ __launch_bounds__(64, 1) void gru_kernel(
    const float* __restrict__ x,
    const float* __restrict__ w_ih,
    const float* __restrict__ w_hh,
    const float* __restrict__ b_ih,
    const float* __restrict__ b_hh,
    float* __restrict__ out)
{
    const int lane = threadIdx.x;
    const int j = lane & 7;
    const int bg = (blockIdx.x << 3) + (lane >> 3);

    // x-side weights: natural column pairs (2p, 2p+1)
    f32x2 wri[4], wzi[4], wni[4];
    #pragma unroll
    for (int p = 0; p < 4; ++p) {
        wri[p] = (f32x2){w_ih[j * 8 + 2 * p],        w_ih[j * 8 + 2 * p + 1]};
        wzi[p] = (f32x2){w_ih[(8 + j) * 8 + 2 * p],  w_ih[(8 + j) * 8 + 2 * p + 1]};
        wni[p] = (f32x2){w_ih[(16 + j) * 8 + 2 * p], w_ih[(16 + j) * 8 + 2 * p + 1]};
    }
    // h-side weights: butterfly-permuted columns j ^ MK[m]
    f32x2 wrh[4], wzh[4], wnh[4];
    #pragma unroll
    for (int p = 0; p < 4; ++p) {
        const int c0 = j ^ MK_[2 * p], c1 = j ^ MK_[2 * p + 1];
        wrh[p] = (f32x2){w_hh[j * 8 + c0],        w_hh[j * 8 + c1]};
        wzh[p] = (f32x2){w_hh[(8 + j) * 8 + c0],  w_hh[(8 + j) * 8 + c1]};
        wnh[p] = (f32x2){w_hh[(16 + j) * 8 + c0], w_hh[(16 + j) * 8 + c1]};
    }
    const float bri = b_ih[j], bzi = b_ih[8 + j], bni = b_ih[16 + j];
    const float brh = b_hh[j], bzh = b_hh[8 + j], bnh = b_hh[16 + j];

    const float* xp = x + (size_t)bg * HH;
    float* op = out + (size_t)bg * HH + j;
    float* hlast = out + (size_t)SS * BB * HH + (size_t)bg * HH + j;

    float4 xA[16], xB[16];

    // prologue: group 0 -> A (one exposed cold-start latency)
    #pragma unroll
    for (int u = 0; u < 8; ++u) {
        const float* p = xp + (size_t)u * XSTRIDE;
        xA[2 * u]     = *(const float4*)p;
        xA[2 * u + 1] = *(const float4*)(p + 4);
    }
    __builtin_amdgcn_sched_barrier(0);

    float h = 0.0f;
    f32x2 hv2[4] = {{0,0},{0,0},{0,0},{0,0}};  // h==0 at step 0

    // 128 groups of 8 steps; ping-pong A/B. sched_barrier pins the load
    // blocks so the scheduler cannot sink them (round 2: VGPR=88 proved it
    // collapsed the prefetch distance to ~0).
    for (int g = 0; g < 128; g += 2) {
        {   // issue loads for group g+1 -> B (used 8 steps ~ 1000+ cyc later)
            const float* bp = xp + (size_t)(g + 1) * 8 * XSTRIDE;
            #pragma unroll
            for (int u = 0; u < 8; ++u) {
                const float* p = bp + (size_t)u * XSTRIDE;
                xB[2 * u]     = *(const float4*)p;
                xB[2 * u + 1] = *(const float4*)(p + 4);
            }
        }
        __builtin_amdgcn_sched_barrier(0);
        #pragma unroll
        for (int u = 0; u < 8; ++u) GSTEP(xA[2 * u], xA[2 * u + 1], g * 8 + u);
        {   // issue loads for group g+2 -> A
            const int ga = (g + 2 < 128) ? (g + 2) : 127;
            const float* ap = xp + (size_t)ga * 8 * XSTRIDE;
            #pragma unroll
            for (int u = 0; u < 8; ++u) {
                const float* p = ap + (size_t)u * XSTRIDE;
                xA[2 * u]     = *(const float4*)p;
                xA[2 * u + 1] = *(const float4*)(p + 4);
            }
        }
        __builtin_amdgcn_sched_barrier(0);
        #pragma unroll
        for (int u = 0; u < 8; ++u) GSTEP(xB[2 * u], xB[2 * u + 1], (g + 1) * 8 + u);
    }
    *hlast = h;
}

extern "C" void kernel_launch(void* const* d_in, const int* in_sizes, int n_in,
                              void* d_out, int out_size, void* d_ws, size_t ws_size,
                              hipStream_t stream) {
    const float* x    = (const float*)d_in[0];
    const float* w_ih = (const float*)d_in[1];
    const float* w_hh = (const float*)d_in[2];
    const float* b_ih = (const float*)d_in[3];
    const float* b_hh = (const float*)d_in[4];
    float* out = (float*)d_out;
    gru_kernel<<<BB / 8, 64, 0, stream>>>(x, w_ih, w_hh, b_ih, b_hh, out);
}

// Round 4
// 150.969 us; speedup vs baseline: 3.0460x; 1.0235x over previous
//
#include <hip/hip_runtime.h>

#define SS 1024
#define BB 4096
#define HH 8
#define XSTRIDE (BB * HH)   // floats per timestep slice

typedef float f32x2 __attribute__((ext_vector_type(2)));

// Raw-HW transcendentals: v_exp_f32 (2^x) + v_rcp_f32. Accumulated absmax
// has held at 3.9e-3 vs 1.95e-2 threshold for two rounds.
__device__ __forceinline__ float fsig(float x) {
    return __builtin_amdgcn_rcpf(1.0f + __builtin_amdgcn_exp2f(-1.4426950408889634f * x));
}
__device__ __forceinline__ float ftanh(float x) {
    return 1.0f - 2.0f * __builtin_amdgcn_rcpf(1.0f + __builtin_amdgcn_exp2f(2.8853900817779268f * x));
}

// DPP cross-lane (VALU pipe, no DS): xor1/xor2 via quad_perm, xor7 via
// row_half_mirror (i -> 7-i == i^7 within each aligned 8-lane half-row).
__device__ __forceinline__ int dpp_x1(int v) {
    return __builtin_amdgcn_mov_dpp(v, 0xB1, 0xF, 0xF, true);   // quad_perm [1,0,3,2]
}
__device__ __forceinline__ int dpp_x2(int v) {
    return __builtin_amdgcn_mov_dpp(v, 0x4E, 0xF, 0xF, true);   // quad_perm [2,3,0,1]
}
__device__ __forceinline__ int dpp_x7(int v) {
    return __builtin_amdgcn_mov_dpp(v, 0x141, 0xF, 0xF, true);  // row_half_mirror
}

// Butterfly register m holds h[j ^ MK[m]]; h-side weights pre-permuted to match.
__device__ __constant__ int MK_[8] = {0, 1, 2, 3, 7, 6, 5, 4};

// X-phase: input-side pre-activations for one step. r/z get BOTH biases
// folded; n keeps h-side bias separate (r multiplies the h-side only).
#define XSTEP(X0, X1, U) do {                                                          \
    f32x2 a0_ = {(X0).x, (X0).y}, a1_ = {(X0).z, (X0).w};                              \
    f32x2 a2_ = {(X1).x, (X1).y}, a3_ = {(X1).z, (X1).w};                              \
    f32x2 sr_ = {bias_r, 0.0f}, sz_ = {bias_z, 0.0f}, sn_ = {bni, 0.0f};               \
    sr_ = __builtin_elementwise_fma(a0_, wri[0], sr_);                                 \
    sr_ = __builtin_elementwise_fma(a1_, wri[1], sr_);                                 \
    sr_ = __builtin_elementwise_fma(a2_, wri[2], sr_);                                 \
    sr_ = __builtin_elementwise_fma(a3_, wri[3], sr_);                                 \
    sz_ = __builtin_elementwise_fma(a0_, wzi[0], sz_);                                 \
    sz_ = __builtin_elementwise_fma(a1_, wzi[1], sz_);                                 \
    sz_ = __builtin_elementwise_fma(a2_, wzi[2], sz_);                                 \
    sz_ = __builtin_elementwise_fma(a3_, wzi[3], sz_);                                 \
    sn_ = __builtin_elementwise_fma(a0_, wni[0], sn_);                                 \
    sn_ = __builtin_elementwise_fma(a1_, wni[1], sn_);                                 \
    sn_ = __builtin_elementwise_fma(a2_, wni[2], sn_);                                 \
    sn_ = __builtin_elementwise_fma(a3_, wni[3], sn_);                                 \
    xr[U] = sr_.x + sr_.y; xz[U] = sz_.x + sz_.y; xn[U] = sn_.x + sn_.y;               \
} while (0)

// R-phase: recurrence-only step. Accumulators start at {x_pre, 0} so only one
// horizontal add sits before each sigmoid.
#define RSTEP(U, SIDX) do {                                                            \
    f32x2 hr2 = {xr[U], 0.0f}, hz2 = {xz[U], 0.0f}, hn2 = {bnh, 0.0f};                 \
    _Pragma("unroll")                                                                  \
    for (int p_ = 0; p_ < 4; ++p_) {                                                   \
        hr2 = __builtin_elementwise_fma(hv2[p_], wrh[p_], hr2);                        \
        hz2 = __builtin_elementwise_fma(hv2[p_], wzh[p_], hz2);                        \
        hn2 = __builtin_elementwise_fma(hv2[p_], wnh[p_], hn2);                        \
    }                                                                                  \
    const float r_ = fsig(hr2.x + hr2.y);                                              \
    const float z_ = fsig(hz2.x + hz2.y);                                              \
    const float n_ = ftanh(xn[U] + r_ * (hn2.x + hn2.y));                              \
    h = n_ + z_ * (h - n_);                                                            \
    const int hb_ = __float_as_int(h);                                                 \
    const int t1_ = dpp_x1(hb_);                                                       \
    const int t2_ = dpp_x2(hb_);                                                       \
    const int t3_ = dpp_x2(t1_);                                                       \
    const int t4_ = dpp_x7(hb_);                                                       \
    const int t5_ = dpp_x7(t1_);                                                       \
    const int t6_ = dpp_x7(t2_);                                                       \
    const int t7_ = dpp_x7(t3_);                                                       \
    hv2[0] = (f32x2){h, __int_as_float(t1_)};                                          \
    hv2[1] = (f32x2){__int_as_float(t2_), __int_as_float(t3_)};                        \
    hv2[2] = (f32x2){__int_as_float(t4_), __int_as_float(t5_)};                        \
    hv2[3] = (f32x2){__int_as_float(t6_), __int_as_float(t7_)};                        \
    op[(size_t)(SIDX) * XSTRIDE] = h;                                                  \
} while (0)

__global__ __launch_bounds__(64, 1) void gru_kernel(
    const float* __restrict__ x,
    const float* __restrict__ w_ih,
    const float* __restrict__ w_hh,
    const float* __restrict__ b_ih,
    const float* __restrict__ b_hh,
    float* __restrict__ out)
{
    const int lane = threadIdx.x;
    const int j = lane & 7;
    const int bg = (blockIdx.x << 3) + (lane >> 3);

    // x-side weights: natural column pairs
    f32x2 wri[4], wzi[4], wni[4];
    #pragma unroll
    for (int p = 0; p < 4; ++p) {
        wri[p] = (f32x2){w_ih[j * 8 + 2 * p],        w_ih[j * 8 + 2 * p + 1]};
        wzi[p] = (f32x2){w_ih[(8 + j) * 8 + 2 * p],  w_ih[(8 + j) * 8 + 2 * p + 1]};
        wni[p] = (f32x2){w_ih[(16 + j) * 8 + 2 * p], w_ih[(16 + j) * 8 + 2 * p + 1]};
    }
    // h-side weights: butterfly-permuted columns j ^ MK[m]
    f32x2 wrh[4], wzh[4], wnh[4];
    #pragma unroll
    for (int p = 0; p < 4; ++p) {
        const int c0 = j ^ MK_[2 * p], c1 = j ^ MK_[2 * p + 1];
        wrh[p] = (f32x2){w_hh[j * 8 + c0],        w_hh[j * 8 + c1]};
        wzh[p] = (f32x2){w_hh[(8 + j) * 8 + c0],  w_hh[(8 + j) * 8 + c1]};
        wnh[p] = (f32x2){w_hh[(16 + j) * 8 + c0], w_hh[(16 + j) * 8 + c1]};
    }
    const float bri = b_ih[j], bzi = b_ih[8 + j], bni = b_ih[16 + j];
    const float brh = b_hh[j], bzh = b_hh[8 + j], bnh = b_hh[16 + j];
    const float bias_r = bri + brh, bias_z = bzi + bzh;

    const float* xp = x + (size_t)bg * HH;
    float* op = out + (size_t)bg * HH + j;
    float* hlast = out + (size_t)SS * BB * HH + (size_t)bg * HH + j;

    float4 xA[16], xB[16];

    // prologue: group 0 -> A (one exposed cold-start latency)
    #pragma unroll
    for (int u = 0; u < 8; ++u) {
        const float* p = xp + (size_t)u * XSTRIDE;
        xA[2 * u]     = *(const float4*)p;
        xA[2 * u + 1] = *(const float4*)(p + 4);
    }
    __builtin_amdgcn_sched_barrier(0);

    float h = 0.0f;
    f32x2 hv2[4] = {{0,0},{0,0},{0,0},{0,0}};
    float xr[8], xz[8], xn[8];

    // 128 groups of 8 steps; ping-pong A/B. sched_barrier pins only the load
    // blocks; X-phase + R-phase share one region so the scheduler fills the
    // recurrence chain's transcendental stalls with later steps' x-dots.
    for (int g = 0; g < 128; g += 2) {
        {   // loads for group g+1 -> B
            const float* bp = xp + (size_t)(g + 1) * 8 * XSTRIDE;
            #pragma unroll
            for (int u = 0; u < 8; ++u) {
                const float* p = bp + (size_t)u * XSTRIDE;
                xB[2 * u]     = *(const float4*)p;
                xB[2 * u + 1] = *(const float4*)(p + 4);
            }
        }
        __builtin_amdgcn_sched_barrier(0);
        #pragma unroll
        for (int u = 0; u < 8; ++u) XSTEP(xA[2 * u], xA[2 * u + 1], u);
        #pragma unroll
        for (int u = 0; u < 8; ++u) RSTEP(u, g * 8 + u);
        {   // loads for group g+2 -> A
            const int ga = (g + 2 < 128) ? (g + 2) : 127;
            const float* ap = xp + (size_t)ga * 8 * XSTRIDE;
            #pragma unroll
            for (int u = 0; u < 8; ++u) {
                const float* p = ap + (size_t)u * XSTRIDE;
                xA[2 * u]     = *(const float4*)p;
                xA[2 * u + 1] = *(const float4*)(p + 4);
            }
        }
        __builtin_amdgcn_sched_barrier(0);
        #pragma unroll
        for (int u = 0; u < 8; ++u) XSTEP(xB[2 * u], xB[2 * u + 1], u);
        #pragma unroll
        for (int u = 0; u < 8; ++u) RSTEP(u, (g + 1) * 8 + u);
    }
    *hlast = h;
}

extern "C" void kernel_launch(void* const* d_in, const int* in_sizes, int n_in,
                              void* d_out, int out_size, void* d_ws, size_t ws_size,
                              hipStream_t stream) {
    const float* x    = (const float*)d_in[0];
    const float* w_ih = (const float*)d_in[1];
    const float* w_hh = (const float*)d_in[2];
    const float* b_ih = (const float*)d_in[3];
    const float* b_hh = (const float*)d_in[4];
    float* out = (float*)d_out;
    gru_kernel<<<BB / 8, 64, 0, stream>>>(x, w_ih, w_hh, b_ih, b_hh, out);
}